// Round 8
// baseline (208.058 us; speedup 1.0000x reference)
//
#include <hip/hip_runtime.h>
#include <hip/hip_bf16.h>

// Problem constants
#define BATCH 16
#define CH    512
#define NPIX  1024
#define GRP   32
#define CPG   16

typedef __attribute__((ext_vector_type(8))) short bf16x8;
typedef __attribute__((ext_vector_type(4))) float f32x4;

__device__ __forceinline__ ushort f2b(float f) {
    union { float f; unsigned u; } v; v.f = f;
    unsigned u = v.u;
    u += 0x7FFF + ((u >> 16) & 1);   // round-to-nearest-even
    return (ushort)(u >> 16);
}

// async global->LDS, 16B per lane. LDS dest must be wave-uniform base + lane*16.
#define GLD16(gp, lp) __builtin_amdgcn_global_load_lds( \
    (__attribute__((address_space(1))) void*)(gp), \
    (__attribute__((address_space(3))) void*)(lp), 16, 0, 0)

// ---------------- fused GroupNorm + weight conversion (R11, neutral-kept) ------
__global__ __launch_bounds__(256) void gn_fused(
    const float* __restrict__ x, const float* __restrict__ gamma,
    const float* __restrict__ beta, ushort* __restrict__ hT,
    const float* __restrict__ wq, const float* __restrict__ wp,
    ushort* __restrict__ wq_b, ushort* __restrict__ wp_b,
    float* __restrict__ rowsum) {
    __shared__ float xs[CPG * NPIX];          // 64 KB
    __shared__ float as[4], bs[4];
    int g = blockIdx.x, b = blockIdx.y;

    // folded weight conversion: 8 consecutive f32 per thread -> ushort8 store
    {
        int bid = g + GRP * b;                        // 0..511
        int base = bid * 2048 + threadIdx.x * 8;
        const float* srcp = (base < 786432) ? (wq + base) : (wp + (base - 786432));
        ushort*      dstp = (base < 786432) ? (wq_b + base) : (wp_b + (base - 786432));
        float4 a = *(const float4*)srcp;
        float4 c = *(const float4*)(srcp + 4);
        ushort t8[8] = {f2b(a.x), f2b(a.y), f2b(a.z), f2b(a.w),
                        f2b(c.x), f2b(c.y), f2b(c.z), f2b(c.w)};
        *(uint4*)dstp = *(const uint4*)t8;
        if (bid < 16) {
            float4 z = {0.f, 0.f, 0.f, 0.f};
            ((float4*)rowsum)[bid * 256 + threadIdx.x] = z;   // 16*256*4 = 16384
        }
    }

    const float4* p = (const float4*)(x + ((size_t)b * CH + g * CPG) * NPIX); // 16384 contiguous
    float4* xs4 = (float4*)xs;
    float s = 0.f, ss = 0.f;
    for (int i = threadIdx.x; i < 4096; i += 256) {
        float4 v = p[i];
        xs4[i] = v;
        s  += v.x + v.y + v.z + v.w;
        ss += v.x*v.x + v.y*v.y + v.z*v.z + v.w*v.w;
    }
    for (int o = 1; o < 64; o <<= 1) { s += __shfl_xor(s, o); ss += __shfl_xor(ss, o); }
    int w = threadIdx.x >> 6;
    if ((threadIdx.x & 63) == 0) { as[w] = s; bs[w] = ss; }
    __syncthreads();                          // also covers xs visibility
    s  = as[0] + as[1] + as[2] + as[3];
    ss = bs[0] + bs[1] + bs[2] + bs[3];
    float m   = s * (1.0f / 16384.0f);
    float var = ss * (1.0f / 16384.0f) - m * m;
    float r   = rsqrtf(var + 1e-5f);

    int c0 = g * CPG;
    float ga[CPG], be[CPG];
#pragma unroll
    for (int c = 0; c < CPG; c++) {
        float gg = gamma[c0 + c] * r;
        ga[c] = gg;
        be[c] = beta[c0 + c] - m * gg;
    }
    ushort tmp[CPG];
#pragma unroll
    for (int i = 0; i < 4; i++) {
        int n = threadIdx.x + i * 256;
#pragma unroll
        for (int c = 0; c < CPG; c++)
            tmp[c] = f2b(xs[c * NPIX + n] * ga[c] + be[c]);   // lanes hit distinct banks
        uint4* dst = (uint4*)(hT + ((size_t)b * NPIX + n) * CH + c0);
        dst[0] = *(const uint4*)&tmp[0];
        dst[1] = *(const uint4*)&tmp[8];
    }
}

// ---------------- generic bf16 gemm_bt<EPI,BM,BN> (R3 structure, proven best) ----
// Single-buffered BK=64, global_load_lds width=16, XOR-swizzled LDS; XCD-aware
// batch-chunk remap. CLOSED levers (measured): flash-fusion (R7: 158us); LDS
// epilogue reorg (R8: +12.6us); BK=64 dbuf @128^2 (R9: occupancy halved); BK=32
// dbuf (R10: barrier rate 2x). 128^2 GEMMs want the plain 2-barrier loop + TLP.
#define BK 64

template<int EPI, int BMt, int BNt>
__global__ __launch_bounds__(256, 4) void gemm_bt(
    const ushort* __restrict__ A, long sA, int lda,
    const ushort* __restrict__ Bt, long sB, int ldb,
    int K,
    void* __restrict__ Out, long sO, int ldo,
    const float* __restrict__ bias,
    const float* __restrict__ resid,
    ushort* __restrict__ vout,
    float* __restrict__ rowsum,
    float scale) {
    constexpr int FM = BMt / 32;
    constexpr int FN = BNt / 32;
    constexpr int SA = BMt / 32;
    constexpr int SB = BNt / 32;
    __shared__ __align__(16) ushort sh[(BMt + BNt) * BK];
    ushort* As = sh;
    ushort* Bs = sh + BMt * BK;

    int nx = gridDim.x, ny = gridDim.y;
    int L = blockIdx.x + nx * (blockIdx.y + ny * blockIdx.z);
    int per = (nx * ny * (int)gridDim.z) >> 3;
    int wid = (L & 7) * per + (L >> 3);
    int bx = wid % nx; wid /= nx;
    int by = wid % ny;
    int b  = wid / ny;

    A  += (size_t)b * sA;
    Bt += (size_t)b * sB;
    int m0 = by * BMt, n0 = bx * BNt;
    int tid = threadIdx.x;
    int lane = tid & 63;
    int wave = tid >> 6;
    int q = lane >> 4, l = lane & 15;
    int wm = (wave >> 1) * (BMt / 2), wn = (wave & 1) * (BNt / 2);

    int aoff[SA], boff[SB], lofa[SA], lofb[SB];
#pragma unroll
    for (int i = 0; i < SA; i++) {
        int p = tid + i * 256, r = p >> 3, g = (p & 7) ^ (r & 7);
        aoff[i] = (m0 + r) * lda + g * 8;
        lofa[i] = p * 8;
    }
#pragma unroll
    for (int i = 0; i < SB; i++) {
        int p = tid + i * 256, r = p >> 3, g = (p & 7) ^ (r & 7);
        boff[i] = (n0 + r) * ldb + g * 8;
        lofb[i] = p * 8;
    }

    int offA[FM][2], offB[FN][2];
#pragma unroll
    for (int mi = 0; mi < FM; mi++) {
        int r = wm + mi * 16 + l;
#pragma unroll
        for (int kk = 0; kk < 2; kk++)
            offA[mi][kk] = r * 64 + ((((kk << 2) | q) ^ (r & 7)) * 8);
    }
#pragma unroll
    for (int ni = 0; ni < FN; ni++) {
        int r = wn + ni * 16 + l;
#pragma unroll
        for (int kk = 0; kk < 2; kk++)
            offB[ni][kk] = r * 64 + ((((kk << 2) | q) ^ (r & 7)) * 8);
    }

    f32x4 zero = {0.f, 0.f, 0.f, 0.f};
    f32x4 acc[FM][FN];
#pragma unroll
    for (int mi = 0; mi < FM; mi++)
#pragma unroll
        for (int ni = 0; ni < FN; ni++) acc[mi][ni] = zero;

    for (int k0 = 0; k0 < K; k0 += BK) {
        __syncthreads();
#pragma unroll
        for (int i = 0; i < SA; i++) GLD16(A + aoff[i] + k0, As + lofa[i]);
#pragma unroll
        for (int i = 0; i < SB; i++) GLD16(Bt + boff[i] + k0, Bs + lofb[i]);
        __syncthreads();
#pragma unroll
        for (int kk = 0; kk < 2; kk++) {
            bf16x8 af[FM], bfr[FN];
#pragma unroll
            for (int mi = 0; mi < FM; mi++) af[mi]  = *(const bf16x8*)(As + offA[mi][kk]);
#pragma unroll
            for (int ni = 0; ni < FN; ni++) bfr[ni] = *(const bf16x8*)(Bs + offB[ni][kk]);
#pragma unroll
            for (int mi = 0; mi < FM; mi++)
#pragma unroll
                for (int ni = 0; ni < FN; ni++)
                    acc[mi][ni] = __builtin_amdgcn_mfma_f32_16x16x32_bf16(
                        af[mi], bfr[ni], acc[mi][ni], 0, 0, 0);
        }
    }

    // epilogue; C/D frag: row m = q*4+reg, col n = l (m89-verified mapping)
    if (EPI == 0) {
        if (n0 >= 1024) {
            __syncthreads();
#pragma unroll
            for (int mi = 0; mi < FM; mi++)
#pragma unroll
                for (int ni = 0; ni < FN; ni++) {
                    int nl = wn + ni * 16 + l;
                    float bi = bias[n0 + nl];
#pragma unroll
                    for (int rg = 0; rg < 4; rg++) {
                        int ml = wm + mi * 16 + q * 4 + rg;
                        int pos = (ml >> 3) ^ (nl & 15);
                        sh[nl * 128 + pos * 8 + (ml & 7)] = f2b(acc[mi][ni][rg] + bi);
                    }
                }
            __syncthreads();
#pragma unroll
            for (int i = 0; i < 8; i++) {
                int idx = tid + i * 256;
                int nl = idx >> 4, ch = idx & 15;
                int g2 = ch ^ (nl & 15);
                uint4 val = *(const uint4*)&sh[nl * 128 + g2 * 8];
                *(uint4*)(vout + (size_t)b * (512 * 1024)
                          + (size_t)(n0 - 1024 + nl) * 1024 + m0 + ch * 8) = val;
            }
            return;
        }
#pragma unroll
        for (int mi = 0; mi < FM; mi++)
#pragma unroll
            for (int ni = 0; ni < FN; ni++) {
                int n = n0 + wn + ni * 16 + l;
                float bi = bias[n];
#pragma unroll
                for (int rg = 0; rg < 4; rg++) {
                    int m = m0 + wm + mi * 16 + q * 4 + rg;
                    ((ushort*)Out)[(size_t)b * sO + (size_t)m * ldo + n] =
                        f2b(acc[mi][ni][rg] + bi);
                }
            }
        return;
    }
#pragma unroll
    for (int mi = 0; mi < FM; mi++) {
        float inv[4];
        if (EPI == 2) {
#pragma unroll
            for (int rg = 0; rg < 4; rg++)
                inv[rg] = 1.0f / rowsum[b * NPIX + m0 + wm + mi * 16 + q * 4 + rg];
        }
#pragma unroll
        for (int ni = 0; ni < FN; ni++) {
            int mbase = m0 + wm + mi * 16 + q * 4;
            int n = n0 + wn + ni * 16 + l;
#pragma unroll
            for (int rg = 0; rg < 4; rg++) {
                int m = mbase + rg;
                float v = acc[mi][ni][rg];
                if (EPI == 2) {
                    ((ushort*)Out)[(size_t)b * sO + (size_t)m * ldo + n] = f2b(v * inv[rg]);
                } else {
                    v += bias[m] + resid[(size_t)b * sO + (size_t)m * ldo + n];
                    ((float*)Out)[(size_t)b * sO + (size_t)m * ldo + n] = v;
                }
            }
        }
    }
}

// ---------------- MM2 at 256^2 geometry (R12) ----------------
// M=N=1024, K=512 -> grid (4,4,16) = 256 blocks = exactly 1/CU. 8 waves (2Mx4N),
// wave tile 128x64 (FM=8, FN=4, acc=128 VGPR). Double-buffered BK=64 with
// counted vmcnt(8) + raw barriers (R9's correctness-proven loop): latency hiding
// is INTRA-block here — the 64-MFMA compute phase (~320cy) covers the L2 latency
// of the prefetched tile, so the 1-block/CU occupancy that killed R9 at 128^2
// doesn't apply. 16 barriers/kernel, each amortizing 4x the MFMA of the R3 loop.
// LDS 128 KB (2 x 64 KB buffers). q,k panels are XCD-L2-hot (2 MB/batch).
__global__ __launch_bounds__(512, 2) void mm2_qk(
    const ushort* __restrict__ qk, ushort* __restrict__ u,
    float* __restrict__ rowsum) {
    constexpr int BM = 256, BN = 256;
    constexpr int SA = 4, SB = 4;
    constexpr int BUF = (BM + BN) * BK;       // 32768 ushorts = 64 KB
    __shared__ __align__(16) ushort sh[2 * BUF];

    // XCD batch-affinity remap: 256 blocks, 32/XCD = 2 batches (matches gemm_bt's
    // mapping so u stays on the producer XCD for MM3)
    int L = blockIdx.x + 4 * (blockIdx.y + 4 * blockIdx.z);
    int wid = (L & 7) * 32 + (L >> 3);
    int bx = wid & 3;
    int by = (wid >> 2) & 3;
    int b  = wid >> 4;

    const ushort* A  = qk + (size_t)b * 1048576;   // q: rows n, cols 0..511
    const ushort* Bt = A + 512;                    // k: rows n, cols 512..1023
    int m0 = by * BM, n0 = bx * BN;
    int tid = threadIdx.x;
    int lane = tid & 63;
    int wave = tid >> 6;
    int q = lane >> 4, l = lane & 15;
    int wm = (wave >> 2) * 128, wn = (wave & 3) * 64;

    // staging (512 threads x 4 granules per operand): granule p; r=p>>3, stored
    // pos p&7 holds global granule g=(p&7)^(r&7)  [same swizzle as gemm_bt]
    int aoff[SA], boff[SB], lof[SA];
#pragma unroll
    for (int i = 0; i < SA; i++) {
        int p = tid + i * 512, r = p >> 3, g = (p & 7) ^ (r & 7);
        aoff[i] = (m0 + r) * 1024 + g * 8;
        boff[i] = (n0 + r) * 1024 + g * 8;
        lof[i]  = p * 8;
    }

    // frag offsets: row r, k-chunk kk: granule G=kk*4+q stored at G^(r&7)
    int offA[8][2], offB[4][2];
#pragma unroll
    for (int mi = 0; mi < 8; mi++) {
        int r = wm + mi * 16 + l;
#pragma unroll
        for (int kk = 0; kk < 2; kk++)
            offA[mi][kk] = r * 64 + ((((kk << 2) | q) ^ (r & 7)) * 8);
    }
#pragma unroll
    for (int ni = 0; ni < 4; ni++) {
        int r = wn + ni * 16 + l;
#pragma unroll
        for (int kk = 0; kk < 2; kk++)
            offB[ni][kk] = r * 64 + ((((kk << 2) | q) ^ (r & 7)) * 8);
    }

    f32x4 zero = {0.f, 0.f, 0.f, 0.f};
    f32x4 acc[8][4];
#pragma unroll
    for (int mi = 0; mi < 8; mi++)
#pragma unroll
        for (int ni = 0; ni < 4; ni++) acc[mi][ni] = zero;

    // prologue: stage tile 0 into buffer 0
#pragma unroll
    for (int i = 0; i < SA; i++) GLD16(A + aoff[i], sh + lof[i]);
#pragma unroll
    for (int i = 0; i < SB; i++) GLD16(Bt + boff[i], sh + BM * BK + lof[i]);

    for (int t = 0; t < 8; t++) {
        const int cur = t & 1;
        const ushort* Asc = sh + cur * BUF;
        const ushort* Bsc = Asc + BM * BK;
        if (t < 7) {
            ushort* Asn = sh + (cur ^ 1) * BUF;
            ushort* Bsn = Asn + BM * BK;
            int k1 = (t + 1) * BK;
#pragma unroll
            for (int i = 0; i < SA; i++) GLD16(A + aoff[i] + k1, Asn + lof[i]);
#pragma unroll
            for (int i = 0; i < SB; i++) GLD16(Bt + boff[i] + k1, Bsn + lof[i]);
            asm volatile("s_waitcnt vmcnt(%0)" :: "i"(SA + SB) : "memory");
        } else {
            asm volatile("s_waitcnt vmcnt(0)" ::: "memory");
        }
        __builtin_amdgcn_s_barrier();
        __builtin_amdgcn_sched_barrier(0);
#pragma unroll
        for (int kk = 0; kk < 2; kk++) {
            bf16x8 af[8], bfr[4];
#pragma unroll
            for (int mi = 0; mi < 8; mi++) af[mi]  = *(const bf16x8*)(Asc + offA[mi][kk]);
#pragma unroll
            for (int ni = 0; ni < 4; ni++) bfr[ni] = *(const bf16x8*)(Bsc + offB[ni][kk]);
            __builtin_amdgcn_s_setprio(1);
#pragma unroll
            for (int mi = 0; mi < 8; mi++)
#pragma unroll
                for (int ni = 0; ni < 4; ni++)
                    acc[mi][ni] = __builtin_amdgcn_mfma_f32_16x16x32_bf16(
                        af[mi], bfr[ni], acc[mi][ni], 0, 0, 0);
            __builtin_amdgcn_s_setprio(0);
        }
        __builtin_amdgcn_sched_barrier(0);
        __builtin_amdgcn_s_barrier();
    }

    // epilogue: u = exp(s*scale) bf16 + atomic f32 row sums
    const float scale = 0.044194173824159216f;
#pragma unroll
    for (int mi = 0; mi < 8; mi++) {
        float rsum4[4] = {0.f, 0.f, 0.f, 0.f};
#pragma unroll
        for (int ni = 0; ni < 4; ni++) {
            int n = n0 + wn + ni * 16 + l;
#pragma unroll
            for (int rg = 0; rg < 4; rg++) {
                int m = m0 + wm + mi * 16 + q * 4 + rg;
                float uu = __expf(acc[mi][ni][rg] * scale);
                rsum4[rg] += uu;
                u[(size_t)b * 1048576 + (size_t)m * 1024 + n] = f2b(uu);
            }
        }
#pragma unroll
        for (int rg = 0; rg < 4; rg++) {
            float s = rsum4[rg];
            s += __shfl_xor(s, 1); s += __shfl_xor(s, 2);
            s += __shfl_xor(s, 4); s += __shfl_xor(s, 8);
            if (l == 0)
                atomicAdd(&rowsum[b * NPIX + m0 + wm + mi * 16 + q * 4 + rg], s);
        }
    }
}

extern "C" void kernel_launch(void* const* d_in, const int* in_sizes, int n_in,
                              void* d_out, int out_size, void* d_ws, size_t ws_size,
                              hipStream_t stream) {
    const float* x     = (const float*)d_in[0];
    const float* gamma = (const float*)d_in[1];
    const float* beta  = (const float*)d_in[2];
    const float* wqkv  = (const float*)d_in[3];
    const float* bqkv  = (const float*)d_in[4];
    const float* wproj = (const float*)d_in[5];
    const float* bproj = (const float*)d_in[6];
    float* out = (float*)d_out;
    char* ws = (char*)d_ws;

    // workspace layout (bytes); total ~101 MB
    ushort* wq_b   = (ushort*)(ws + 0);          // 1.5 MB
    ushort* wp_b   = (ushort*)(ws + 1572864);    // 0.5 MB
    float*  rowsum = (float*)(ws + 2101248);     // 64 KB [b][i]
    ushort* hT     = (ushort*)(ws + 2166784);    // 16 MB [b][n][c]  (reused as O1T)
    ushort* qk     = (ushort*)(ws + 18944000);   // 32 MB [b][n][q0..511,k512..1023]
    ushort* vb     = (ushort*)(ws + 52498432);   // 16 MB [b][c][j]
    ushort* u      = (ushort*)(ws + 69275648);   // 32 MB [b][i][j]  exp(s) bf16
    ushort* O1T    = hT;                          // alias: hT dead after MM1

    gn_fused<<<dim3(GRP, BATCH), 256, 0, stream>>>(
        x, gamma, beta, hT, wqkv, wproj, wq_b, wp_b, rowsum);

    // MM1: qkvT[n][o] = sum_c hT[n][c] * Wqkv[o][c]  (M=1024, N=1536, K=512)
    gemm_bt<0, 128, 128><<<dim3(12, 8, BATCH), 256, 0, stream>>>(
        hT, 524288, 512, wq_b, 0, 512, 512,
        qk, 1048576, 1024, bqkv, nullptr, vb, nullptr, 0.f);

    // MM2: u[i][j] = exp(q.k * scale), rowsum[i] += ...  (256^2 pipelined kernel)
    mm2_qk<<<dim3(4, 4, BATCH), 512, 0, stream>>>(qk, u, rowsum);

    // MM3: O1T[i][c] = (sum_j u[i][j] * v[c][j]) / rowsum[i]  (M=1024, N=512, K=1024)
    gemm_bt<2, 128, 64><<<dim3(8, 8, BATCH), 256, 0, stream>>>(
        u, 1048576, 1024, vb, 524288, 1024, 1024,
        O1T, 524288, 512, nullptr, nullptr, nullptr, rowsum, 0.f);

    // MM4: out[o][n] = sum_c Wp[o][c] * O1T[n][c] + bproj[o] + x  (M=512, N=1024, K=512)
    gemm_bt<3, 64, 128><<<dim3(8, 8, BATCH), 256, 0, stream>>>(
        wp_b, 0, 512, O1T, 524288, 512, 512,
        out, 524288, 1024, bproj, x, nullptr, nullptr, 0.f);
}